// Round 9
// baseline (212.243 us; speedup 1.0000x reference)
//
#include <hip/hip_runtime.h>
#include <cstdint>
#include <cstddef>

// Problem: B=8, C=64, H=W=32 -> N=8192 nodes, K=9 neighbors, OUT=64.
// Batches: k = [1024k,1024(k+1)) for k<=6, batch 7 = [7168,8190], batch 8 = {8191}.
// Node g: b = g>>10, hw = g&1023; feature ch of g = x[b*65536 + ch*1024 + hw].
//
// R9 = R7's fused kernel re-partitioned for the register budget:
//  512 thr/block (8 waves, 2/SIMD), 4 rows/wave -> acc[4][16]=64 VGPRs, no
//  spill (R8 failure mode: WRITE_SIZE 140MB scratch). Phase 2 = 4-wide
//  interleaved tournaments, register-neutral (d[4][16] replaces acc[4][16]).
//  Lane l owns candidates c = 4l + 256e + j (slot q = 4e+j).

#define CBUF_STRIDE 1028
#define CBUF_BYTES (64 * CBUF_STRIDE * 2)   // 131,584 B dynamic LDS

__device__ __forceinline__ unsigned mono32(float d) {
  unsigned u = __float_as_uint(d);
  return (u & 0x80000000u) ? ~u : (u | 0x80000000u);
}

__device__ __forceinline__ float rdlane(float v, int src) {
  return __int_as_float(__builtin_amdgcn_readlane(__float_as_int(v), src));
}

__device__ __forceinline__ unsigned short bf16rn(float v) {
  unsigned bits = __float_as_uint(v);
  return (unsigned short)((bits + 0x7FFFu + ((bits >> 16) & 1u)) >> 16);
}

extern "C" __global__ __launch_bounds__(512, 2)
void k_fused(const float* __restrict__ x,
             const float* __restrict__ Wl,
             const float* __restrict__ bl,
             const float* __restrict__ Wr,
             float* __restrict__ out) {
  extern __shared__ unsigned short cbuf[];   // [64][CBUF_STRIDE] bf16
  int t = threadIdx.x;
  int lane = t & 63;
  int w = t >> 6;                            // 0..7
  int n0 = (int)blockIdx.x << 5;             // 32 rows per block
  int s = (n0 >= 7168) ? 7168 : (n0 & ~1023);
  const float* xb = x + ((size_t)(s >> 10) << 16);

  // self features (lane = channel); 4 scattered wave-loads, once
  float rowf[4];
#pragma unroll
  for (int r = 0; r < 4; ++r) {
    int n = n0 + (w << 2) + r;
    rowf[r] = xb[(lane << 10) + (n & 1023)];
  }

  float acc[4][16];
#pragma unroll
  for (int r = 0; r < 4; ++r)
#pragma unroll
    for (int q = 0; q < 16; ++q) acc[r][q] = 0.f;
  float sqc[16];
#pragma unroll
  for (int q = 0; q < 16; ++q) sqc[q] = 0.f;

  // -------- phase 1: channel stream, depth-1 ping-pong --------
  float4 pb[2][4];
#pragma unroll
  for (int e = 0; e < 4; ++e)
    pb[0][e] = *(const float4*)&xb[(lane << 2) + (e << 8)];   // ch 0

#pragma unroll 1
  for (int ch = 0; ch < 64; ++ch) {
    int cur = ch & 1;
    if (ch < 63) {
#pragma unroll
      for (int e = 0; e < 4; ++e)
        pb[cur ^ 1][e] =
            *(const float4*)&xb[((ch + 1) << 10) + (lane << 2) + (e << 8)];
    }
    if ((ch >> 3) == w) {                    // bf16 side-copy: 8 ch per wave
#pragma unroll
      for (int e = 0; e < 4; ++e) {
        ushort4 pk;
        pk.x = bf16rn(pb[cur][e].x);
        pk.y = bf16rn(pb[cur][e].y);
        pk.z = bf16rn(pb[cur][e].z);
        pk.w = bf16rn(pb[cur][e].w);
        *(ushort4*)&cbuf[ch * CBUF_STRIDE + (lane << 2) + (e << 8)] = pk;
      }
    }
    float rv[4];
#pragma unroll
    for (int r = 0; r < 4; ++r) rv[r] = rdlane(rowf[r], ch);
#pragma unroll
    for (int e = 0; e < 4; ++e) {
      float cv[4] = {pb[cur][e].x, pb[cur][e].y, pb[cur][e].z, pb[cur][e].w};
#pragma unroll
      for (int j = 0; j < 4; ++j) {
        int q = (e << 2) + j;
        sqc[q] = fmaf(cv[j], cv[j], sqc[q]);
#pragma unroll
        for (int r = 0; r < 4; ++r)
          acc[r][q] = fmaf(rv[r], cv[j], acc[r][q]);
      }
    }
  }
  __syncthreads();                           // cbuf complete

  // -------- phase 2: 4 interleaved top-9 tournaments + bf16 mean --------
  float sqr[4];
#pragma unroll
  for (int r = 0; r < 4; ++r) {
    int lr = (n0 + (w << 2) + r) - s;
    int lslot = ((lr >> 8) << 2) | (lr & 3);
    int llane = (lr >> 2) & 63;
    float sel = sqc[0];
#pragma unroll
    for (int q = 1; q < 16; ++q) sel = (q == lslot) ? sqc[q] : sel;
    sqr[r] = __shfl(sel, llane, 64);
  }

  bool mrow = (s == 7168);                   // exclude cand 1023 (node 8191)
  unsigned d[4][16];                         // consumes acc's registers
#pragma unroll
  for (int r = 0; r < 4; ++r)
#pragma unroll
    for (int q = 0; q < 16; ++q)
      d[r][q] = mono32((sqr[r] + sqc[q]) - 2.f * acc[r][q]);
  if (mrow && lane == 63) {
#pragma unroll
    for (int r = 0; r < 4; ++r) d[r][15] = 0xFFFFFFFFu;
  }

  // per-lane cached top-2 (strict < keeps earliest slot = smallest c)
  unsigned m1d[4], m2d[4];
  int m1s[4], m2s[4];
#pragma unroll
  for (int r = 0; r < 4; ++r) {
    unsigned a = d[r][0], b = d[r][1];
    if (b < a) { m1d[r] = b; m2d[r] = a; m1s[r] = 1; m2s[r] = 0; }
    else       { m1d[r] = a; m2d[r] = b; m1s[r] = 0; m2s[r] = 1; }
#pragma unroll
    for (int q = 2; q < 16; ++q) {
      unsigned dq = d[r][q];
      bool lt1 = dq < m1d[r], lt2 = dq < m2d[r];
      m2d[r] = lt1 ? m1d[r] : (lt2 ? dq : m2d[r]);
      m2s[r] = lt1 ? m1s[r] : (lt2 ? q : m2s[r]);
      m1d[r] = lt1 ? dq : m1d[r];
      m1s[r] = lt1 ? q : m1s[r];
    }
  }

  unsigned lmd[4], rmask[4];
  int lms[4];
  unsigned staleM = 0;
  float msum[4];
#pragma unroll
  for (int r = 0; r < 4; ++r) {
    lmd[r] = m1d[r]; lms[r] = m1s[r]; rmask[r] = 0u; msum[r] = 0.f;
  }

#pragma unroll 1
  for (int kk = 0; kk < 9; ++kk) {
    unsigned g[4];
#pragma unroll
    for (int r = 0; r < 4; ++r) g[r] = lmd[r];
#pragma unroll
    for (int off = 32; off; off >>= 1) {
#pragma unroll
      for (int r = 0; r < 4; ++r) {
        unsigned o = (unsigned)__shfl_xor((int)g[r], off, 64);
        g[r] = (o < g[r]) ? o : g[r];
      }
    }
    unsigned wc[4];                          // index-min over tying lanes
#pragma unroll
    for (int r = 0; r < 4; ++r) {
      unsigned cc = ((unsigned)lane << 2) | ((unsigned)(lms[r] >> 2) << 8) |
                    (unsigned)(lms[r] & 3);
      wc[r] = (lmd[r] == g[r]) ? cc : 0xFFFFFFFFu;
    }
#pragma unroll
    for (int off = 32; off; off >>= 1) {
#pragma unroll
      for (int r = 0; r < 4; ++r) {
        unsigned o = (unsigned)__shfl_xor((int)wc[r], off, 64);
        wc[r] = (o < wc[r]) ? o : wc[r];
      }
    }
#pragma unroll
    for (int r = 0; r < 4; ++r)              // winner feature (lane = channel)
      msum[r] += __uint_as_float(
          (unsigned)cbuf[lane * CBUF_STRIDE + (int)(wc[r] & 1023u)] << 16);
#pragma unroll
    for (int r = 0; r < 4; ++r) {
      unsigned cc = ((unsigned)lane << 2) | ((unsigned)(lms[r] >> 2) << 8) |
                    (unsigned)(lms[r] & 3);
      if (lmd[r] == g[r] && cc == wc[r]) {   // this lane consumed its min
        rmask[r] |= 1u << lms[r];
        if (!((staleM >> r) & 1u)) {
          lmd[r] = m2d[r]; lms[r] = m2s[r]; staleM |= 1u << r;
        } else {                             // rare: rescan alive slots
          unsigned bd = 0xFFFFFFFFu; int bs = 0;
#pragma unroll
          for (int q = 0; q < 16; ++q) {
            bool alive = ((rmask[r] >> q) & 1u) == 0u;
            bool take = alive && (d[r][q] < bd);
            bd = take ? d[r][q] : bd;
            bs = take ? q : bs;
          }
          lmd[r] = bd; lms[r] = bs;
        }
      }
    }
  }

  float ms[4];
#pragma unroll
  for (int r = 0; r < 4; ++r) {
    int n = n0 + (w << 2) + r;
    ms[r] = (n == 8191) ? rowf[r] : msum[r] / 9.0f;   // singleton: self
  }

  // -------- phase 3: out = mean@Wl^T + bl + self@Wr^T (lane = out ch) -----
  float4 wl4[16], wr4[16];
#pragma unroll
  for (int k = 0; k < 16; ++k) {
    wl4[k] = *(const float4*)&Wl[(lane << 6) + (k << 2)];
    wr4[k] = *(const float4*)&Wr[(lane << 6) + (k << 2)];
  }
  float bias = bl[lane];
#pragma unroll 1
  for (int r = 0; r < 4; ++r) {
    int n = n0 + (w << 2) + r;
    float accL = 0.f, accR = 0.f;
#pragma unroll
    for (int c = 0; c < 64; ++c) {
      float mc = rdlane(ms[r], c);
      float xc = rdlane(rowf[r], c);
      const float* wlp = (const float*)&wl4[c >> 2];
      const float* wrp = (const float*)&wr4[c >> 2];
      accL = fmaf(mc, wlp[c & 3], accL);
      accR = fmaf(xc, wrp[c & 3], accR);
    }
    out[((size_t)n << 6) + lane] = accL + accR + bias;
  }
}

// ---------------------------------------------------------------------------
extern "C" void kernel_launch(void* const* d_in, const int* in_sizes, int n_in,
                              void* d_out, int out_size, void* d_ws, size_t ws_size,
                              hipStream_t stream) {
  const float* x  = (const float*)d_in[0];   // (8,64,32,32)
  const float* Wl = (const float*)d_in[1];   // (64,64)
  const float* bl = (const float*)d_in[2];   // (64,)
  const float* Wr = (const float*)d_in[3];   // (64,64)
  float* out = (float*)d_out;                // (8192,64)

  // dynamic LDS > 64 KB: opt in every call (idempotent, capture-safe)
  hipFuncSetAttribute((const void*)k_fused,
                      hipFuncAttributeMaxDynamicSharedMemorySize, CBUF_BYTES);
  k_fused<<<256, 512, CBUF_BYTES, stream>>>(x, Wl, bl, Wr, out);
}

// Round 10
// 121.046 us; speedup vs baseline: 1.7534x; 1.7534x over previous
//
#include <hip/hip_runtime.h>
#include <cstdint>
#include <cstddef>

// Problem: B=8, C=64, H=W=32 -> N=8192 nodes, K=9 neighbors, OUT=64.
// Batches: k = [1024k,1024(k+1)) for k<=6, batch 7 = [7168,8190], batch 8 = {8191}.
// Node g: b = g>>10, hw = g&1023; feature ch of g = x[b*65536 + ch*1024 + hw].
//
// R10 = R6 (best: 107.2us) + in-tile partial top-9 (no 33.5MB D round-trip):
//  KA: 128x128 distance tile in regs (R6 GEMM verbatim) -> per-(row,tile)
//      top-9 u64 keys via 16-lane quarter butterflies -> part[] (4.7MB).
//  KB: merge 72 keys/row (64-lane butterfly) -> gather + GEMV (R6 verbatim,
//      but fully static j9 indexing; row 8191 = 9x self, no dynamic loop).
// Register discipline (R8/R9 lesson): every reg-array index static; no
// shfl-fed array lives across a non-unrolled loop.

__device__ __forceinline__ unsigned mono32(float d) {
  unsigned u = __float_as_uint(d);
  return (u & 0x80000000u) ? ~u : (u | 0x80000000u);
}

__device__ __forceinline__ float rdlane(float v, int src) {
  return __int_as_float(__builtin_amdgcn_readlane(__float_as_int(v), src));
}

// ---------------------------------------------------------------------------
// KA: distance tile + in-tile top-9.
// ---------------------------------------------------------------------------
__global__ __launch_bounds__(256, 2) void k_dist_topk(const float* __restrict__ x,
                                                      float* __restrict__ xf,
                                                      unsigned long long* __restrict__ part) {
  __shared__ float4 As4[32 * 33];   // [c:32][m4:33] pad -> conflict-free
  __shared__ float4 Bs4[32 * 33];
  __shared__ float sqA[128];
  __shared__ float sqB[128];
  int cx = blockIdx.x;              // 0..7 col-tile
  int i0 = (int)blockIdx.y << 7;    // 0..8064
  int s = (i0 >= 7168) ? 7168 : (i0 & ~1023);
  int j0 = s + (cx << 7);
  const float* xA = x + (((size_t)(i0 >> 10)) << 16) + (i0 & 1023);
  const float* xB = x + (((size_t)(j0 >> 10)) << 16) + (j0 & 1023);
  int t = threadIdx.x;
  int tx = t & 15, ty = t >> 4;

  float acc[8][8];
#pragma unroll
  for (int r = 0; r < 8; ++r)
#pragma unroll
    for (int c = 0; c < 8; ++c) acc[r][c] = 0.f;

#pragma unroll 1
  for (int pass = 0; pass < 2; ++pass) {
    if (pass) __syncthreads();
    int c0 = pass << 5;
#pragma unroll
    for (int i = 0; i < 4; ++i) {
      int u = t + (i << 8);
      int c = u >> 5, m4 = u & 31;
      As4[c * 33 + m4] = *(const float4*)&xA[((size_t)(c0 + c) << 10) + (m4 << 2)];
      Bs4[c * 33 + m4] = *(const float4*)&xB[((size_t)(c0 + c) << 10) + (m4 << 2)];
    }
    __syncthreads();
    // sq partials: ascending-c fmaf chain == dot chain -> d(i,i) == +0
    {
      int m = t & 127;
      const float* base = (t < 128) ? (const float*)As4 : (const float*)Bs4;
      float p = 0.f;
#pragma unroll
      for (int c = 0; c < 32; ++c) {
        float v = base[(c * 33 + (m >> 2)) * 4 + (m & 3)];
        p = fmaf(v, v, p);
      }
      float* dst = (t < 128) ? sqA : sqB;
      if (pass == 0) dst[m] = p; else dst[m] += p;
    }
    if (cx == 0) {                  // xf side-write for KB's gathers
#pragma unroll
      for (int i = 0; i < 16; ++i) {
        int u = t + (i << 8);
        int c = u & 31, m = u >> 5;
        xf[((size_t)(i0 + m) << 6) + c0 + c] =
            ((const float*)As4)[(c * 33 + (m >> 2)) * 4 + (m & 3)];
      }
    }
#pragma unroll 4
    for (int k = 0; k < 32; ++k) {
      float4 a0 = As4[k * 33 + ty];
      float4 a1 = As4[k * 33 + 16 + ty];
      float4 b0 = Bs4[k * 33 + tx];
      float4 b1 = Bs4[k * 33 + 16 + tx];
      float av[8] = {a0.x, a0.y, a0.z, a0.w, a1.x, a1.y, a1.z, a1.w};
      float bv[8] = {b0.x, b0.y, b0.z, b0.w, b1.x, b1.y, b1.z, b1.w};
#pragma unroll
      for (int r = 0; r < 8; ++r)
#pragma unroll
        for (int c = 0; c < 8; ++c)
          acc[r][c] = fmaf(av[r], bv[c], acc[r][c]);
    }
  }
  __syncthreads();                  // sqA/sqB complete

  int rloc[8], cloc[8];
#pragma unroll
  for (int r = 0; r < 4; ++r) { rloc[r] = (ty << 2) + r; rloc[4 + r] = 64 + (ty << 2) + r; }
#pragma unroll
  for (int c = 0; c < 4; ++c) { cloc[c] = (tx << 2) + c; cloc[4 + c] = 64 + (tx << 2) + c; }
  float sqi[8], sqj[8];
#pragma unroll
  for (int r = 0; r < 8; ++r) sqi[r] = sqA[rloc[r]];
#pragma unroll
  for (int c = 0; c < 8; ++c) sqj[c] = sqB[cloc[c]];
  bool excl = (s == 7168) && (cx == 7);   // candidate jj=1023 == node 8191

  // per-row in-tile top-9: row's 128 values live on the 16 lanes sharing ty
  // (quarter q = ty&3); xor-butterfly off {8,4,2,1} stays inside the quarter.
#pragma unroll
  for (int r = 0; r < 8; ++r) {
    int row = i0 + rloc[r];
    unsigned long long k8[8];
#pragma unroll
    for (int c = 0; c < 8; ++c) {
      float dv = sqi[r] + sqj[c] - 2.f * acc[r][c];
      unsigned jj = (unsigned)((cx << 7) + cloc[c]);
      unsigned long long key = ((unsigned long long)mono32(dv) << 32) | jj;
      if (excl && cloc[c] == 127) key = ~0ull;
      k8[c] = key;
    }
    // per-lane cached top-2 (keys unique -> no tie ambiguity)
    unsigned long long m1 = k8[0], m2 = k8[1];
    int s1 = 0, s2 = 1;
    if (m2 < m1) { unsigned long long tt = m1; m1 = m2; m2 = tt; s1 = 1; s2 = 0; }
#pragma unroll
    for (int c = 2; c < 8; ++c) {
      unsigned long long kc = k8[c];
      bool lt1 = kc < m1, lt2 = kc < m2;
      m2 = lt1 ? m1 : (lt2 ? kc : m2);
      s2 = lt1 ? s1 : (lt2 ? c : s2);
      m1 = lt1 ? kc : m1;
      s1 = lt1 ? c : s1;
    }
    unsigned long long lm = m1;
    int lms = s1;
    unsigned rmask = 0;
    bool stale = false;
#pragma unroll
    for (int kk = 0; kk < 9; ++kk) {
      unsigned long long g = lm;
#pragma unroll
      for (int off = 8; off; off >>= 1) {
        unsigned hi = (unsigned)__shfl_xor((int)(unsigned)(g >> 32), off, 64);
        unsigned lo = (unsigned)__shfl_xor((int)(unsigned)g, off, 64);
        unsigned long long o = ((unsigned long long)hi << 32) | lo;
        g = (o < g) ? o : g;
      }
      if (tx == kk) part[((size_t)((row << 3) | cx)) * 9 + kk] = g;
      if (lm == g) {                // unique keys -> exactly one winner lane
        rmask |= 1u << lms;
        if (!stale) { lm = m2; lms = s2; stale = true; }
        else {                      // rare: rescan alive slots
          unsigned long long bd = ~0ull; int bs = 0;
#pragma unroll
          for (int c = 0; c < 8; ++c) {
            bool alive = ((rmask >> c) & 1u) == 0u;
            bool take = alive && (k8[c] < bd);
            bd = take ? k8[c] : bd;
            bs = take ? c : bs;
          }
          lm = bd; lms = bs;
        }
      }
    }
  }
}

// ---------------------------------------------------------------------------
// KB: merge 8x9 partial keys per row -> top-9 -> mean gather + SAGE output.
// ---------------------------------------------------------------------------
__global__ __launch_bounds__(256, 2) void k_merge_out(const unsigned long long* __restrict__ part,
                                                      const float* __restrict__ xf,
                                                      const float* __restrict__ Wl,
                                                      const float* __restrict__ bl,
                                                      const float* __restrict__ Wr,
                                                      float* __restrict__ out) {
  __shared__ float WsL[64][65];
  __shared__ float WsR[64][65];
  int t = threadIdx.x;
#pragma unroll
  for (int i = 0; i < 16; ++i) {
    int lin = t + (i << 8);
    WsL[lin >> 6][lin & 63] = Wl[lin];
    WsR[lin >> 6][lin & 63] = Wr[lin];
  }
  __syncthreads();
  int lane = t & 63;
  float wl[64], wr[64];
#pragma unroll
  for (int c = 0; c < 64; ++c) { wl[c] = WsL[lane][c]; wr[c] = WsR[lane][c]; }
  float bias = bl[lane];
  int w = t >> 6;
  int n0 = ((int)blockIdx.x << 4) + (w << 2);

  unsigned j9[4][9];                // wave-uniform after butterfly
#pragma unroll
  for (int r = 0; r < 4; ++r) {
    int n = n0 + r;
    if (n == 8191) {                // singleton batch: mean(9x self) == self
#pragma unroll
      for (int kk = 0; kk < 9; ++kk) j9[r][kk] = 8191u;
      continue;
    }
    int s = (n >= 7168) ? 7168 : (n & ~1023);
    const unsigned long long* p72 = part + (size_t)n * 72;
    unsigned long long a = p72[lane];
    unsigned long long b2 = (lane < 8) ? p72[64 + lane] : ~0ull;
    unsigned long long lm = (a < b2) ? a : b2;
    unsigned long long nx = (a < b2) ? b2 : a;
#pragma unroll
    for (int kk = 0; kk < 9; ++kk) {
      unsigned long long g = lm;
#pragma unroll
      for (int off = 32; off; off >>= 1) {
        unsigned hi = (unsigned)__shfl_xor((int)(unsigned)(g >> 32), off, 64);
        unsigned lo = (unsigned)__shfl_xor((int)(unsigned)g, off, 64);
        unsigned long long o = ((unsigned long long)hi << 32) | lo;
        g = (o < g) ? o : g;
      }
      j9[r][kk] = (unsigned)s + (unsigned)(g & 1023u);
      if (lm == g) { lm = nx; nx = ~0ull; }   // <=2 keys/lane
    }
  }

  // gather (uniform index -> coalesced 256B rows) + fused GEMV epilogue
  float ms[4], xr[4];
#pragma unroll
  for (int r = 0; r < 4; ++r) {
    int n = n0 + r;
    float msum = 0.f;
#pragma unroll
    for (int k = 0; k < 9; ++k)
      msum += xf[((size_t)j9[r][k] << 6) + lane];
    ms[r] = msum / 9.0f;            // lane c = feature c
    xr[r] = xf[((size_t)n << 6) + lane];
  }
  float accL[4] = {0.f, 0.f, 0.f, 0.f};
  float accR[4] = {0.f, 0.f, 0.f, 0.f};
#pragma unroll
  for (int c = 0; c < 64; ++c) {
#pragma unroll
    for (int r = 0; r < 4; ++r) {
      float mc = rdlane(ms[r], c);
      float xc = rdlane(xr[r], c);
      accL[r] = fmaf(mc, wl[c], accL[r]);
      accR[r] = fmaf(xc, wr[c], accR[r]);
    }
  }
#pragma unroll
  for (int r = 0; r < 4; ++r)
    out[((size_t)(n0 + r) << 6) + lane] = accL[r] + accR[r] + bias;
}

// ---------------------------------------------------------------------------
extern "C" void kernel_launch(void* const* d_in, const int* in_sizes, int n_in,
                              void* d_out, int out_size, void* d_ws, size_t ws_size,
                              hipStream_t stream) {
  const float* x  = (const float*)d_in[0];   // (8,64,32,32)
  const float* Wl = (const float*)d_in[1];   // (64,64)
  const float* bl = (const float*)d_in[2];   // (64,)
  const float* Wr = (const float*)d_in[3];   // (64,64)
  float* out = (float*)d_out;                // (8192,64)

  char* ws = (char*)d_ws;
  float* xf = (float*)(ws);                              //  2,097,152 B
  unsigned long long* part =
      (unsigned long long*)(ws + 2097152);               //  4,718,592 B

  k_dist_topk<<<dim3(8, 64), 256, 0, stream>>>(x, xf, part);
  k_merge_out<<<512, 256, 0, stream>>>(part, xf, Wl, bl, Wr, out);
}

// Round 11
// 115.942 us; speedup vs baseline: 1.8306x; 1.0440x over previous
//
#include <hip/hip_runtime.h>
#include <cstdint>
#include <cstddef>

// Problem: B=8, C=64, H=W=32 -> N=8192 nodes, K=9 neighbors, OUT=64.
// Batches: k = [1024k,1024(k+1)) for k<=6, batch 7 = [7168,8190], batch 8 = {8191}.
// Node g: b = g>>10, hw = g&1023; feature ch of g = x[b*65536 + ch*1024 + hw].
//
// R11 = R7's fused kernel (passed, 64us) rebuilt for latency hiding:
//  1024 thr/block (16 waves -> 4/SIMD at 1 block/CU), 2 rows/wave.
//  Per-wave regs: acc[2][16]=32; peak live ~102 < 128 cap (launch_bounds 1024,4).
//  All register arrays statically indexed (R8/R9 spill lesson).
//  Phase 1: every wave streams all 64 channel planes (L1-kept by barrier per
//  8 ch); explicit cur/nxt prefetch. cbuf bf16 side-copy: wave w owns ch 4w..4w+3.
//  Phase 2: R7's exact per-row tournament (u32 + ballot resolve), 2 rows/wave,
//  16 waves overlap. Phase 3: two-pass W (64 regs each).

#define CBUF_STRIDE 1028
#define CBUF_BYTES (64 * CBUF_STRIDE * 2)   // 131,584 B dynamic LDS

__device__ __forceinline__ unsigned mono32(float d) {
  unsigned u = __float_as_uint(d);
  return (u & 0x80000000u) ? ~u : (u | 0x80000000u);
}

__device__ __forceinline__ unsigned bmin32(unsigned v) {
#pragma unroll
  for (int off = 32; off; off >>= 1) {
    unsigned o = (unsigned)__shfl_xor((int)v, off, 64);
    v = (o < v) ? o : v;
  }
  return v;
}

__device__ __forceinline__ float rdlane(float v, int src) {
  return __int_as_float(__builtin_amdgcn_readlane(__float_as_int(v), src));
}

__device__ __forceinline__ unsigned short bf16rn(float v) {
  unsigned bits = __float_as_uint(v);
  return (unsigned short)((bits + 0x7FFFu + ((bits >> 16) & 1u)) >> 16);
}

extern "C" __global__ __launch_bounds__(1024, 4)
void k_fused(const float* __restrict__ x,
             const float* __restrict__ Wl,
             const float* __restrict__ bl,
             const float* __restrict__ Wr,
             float* __restrict__ out) {
  extern __shared__ unsigned short cbuf[];   // [64][CBUF_STRIDE] bf16
  int t = threadIdx.x;
  int lane = t & 63;
  int w = t >> 6;                            // 0..15
  int n0 = (int)blockIdx.x << 5;             // 32 rows per block
  int s = n0 & ~1023;                        // batch start (==7168 for n0>=7168)
  const float* xb = x + ((size_t)(s >> 10) << 16);

  // self features (lane = channel), 2 rows per wave
  float rowf[2];
#pragma unroll
  for (int r = 0; r < 2; ++r) {
    int n = n0 + (w << 1) + r;
    rowf[r] = xb[(lane << 10) + (n & 1023)];
  }

  float acc[2][16];
#pragma unroll
  for (int r = 0; r < 2; ++r)
#pragma unroll
    for (int q = 0; q < 16; ++q) acc[r][q] = 0.f;
  float sqc[16];
#pragma unroll
  for (int q = 0; q < 16; ++q) sqc[q] = 0.f;

  // -------- phase 1: channel stream (explicit cur/nxt, static indexing) ----
  float4 cur[4], nxt[4];
#pragma unroll
  for (int e = 0; e < 4; ++e)
    cur[e] = *(const float4*)&xb[(lane << 2) + (e << 8)];    // ch 0

#pragma unroll 1
  for (int ch = 0; ch < 64; ++ch) {
    if (ch < 63) {
#pragma unroll
      for (int e = 0; e < 4; ++e)
        nxt[e] = *(const float4*)&xb[((ch + 1) << 10) + (lane << 2) + (e << 8)];
    }
    if ((ch >> 2) == w) {                    // bf16 side-copy: 4 ch per wave
#pragma unroll
      for (int e = 0; e < 4; ++e) {
        ushort4 pk;
        pk.x = bf16rn(cur[e].x);
        pk.y = bf16rn(cur[e].y);
        pk.z = bf16rn(cur[e].z);
        pk.w = bf16rn(cur[e].w);
        *(ushort4*)&cbuf[ch * CBUF_STRIDE + (lane << 2) + (e << 8)] = pk;
      }
    }
    float rv0 = rdlane(rowf[0], ch);
    float rv1 = rdlane(rowf[1], ch);
#pragma unroll
    for (int e = 0; e < 4; ++e) {
      float cv[4] = {cur[e].x, cur[e].y, cur[e].z, cur[e].w};
#pragma unroll
      for (int j = 0; j < 4; ++j) {
        int q = (e << 2) + j;
        sqc[q] = fmaf(cv[j], cv[j], sqc[q]);
        acc[0][q] = fmaf(rv0, cv[j], acc[0][q]);
        acc[1][q] = fmaf(rv1, cv[j], acc[1][q]);
      }
    }
#pragma unroll
    for (int e = 0; e < 4; ++e) cur[e] = nxt[e];
    if ((ch & 7) == 7) __syncthreads();      // keep 16 waves L1-aligned
  }
  __syncthreads();                           // cbuf complete

  // -------- phase 2: per-row top-9 (R7 tournament) + bf16 mean -------------
  bool mrow = (s == 7168);                   // exclude cand 1023 (node 8191)
  float ms[2];
#pragma unroll 1
  for (int r = 0; r < 2; ++r) {
    int n = n0 + (w << 1) + r;
    float rf = (r == 0) ? rowf[0] : rowf[1];
    if (n == 8191) { ms[r] = rf; continue; } // singleton batch: mean = self
    int lr = n - s;
    int lslot = ((lr >> 8) << 2) | (lr & 3); // owner slot of cand c = lr
    int llane = (lr >> 2) & 63;
    float sel = sqc[0];
#pragma unroll
    for (int q = 1; q < 16; ++q) sel = (q == lslot) ? sqc[q] : sel;
    float sqr = __shfl(sel, llane, 64);

    unsigned d[16];
#pragma unroll
    for (int q = 0; q < 16; ++q) {
      float a = (r == 0) ? acc[0][q] : acc[1][q];
      d[q] = mono32((sqr + sqc[q]) - 2.f * a);
    }
    if (mrow && lane == 63) d[15] = 0xFFFFFFFFu;

    // per-lane cached top-2 (strict < keeps earliest slot = smallest c)
    unsigned m1d = d[0], m2d = d[1];
    int m1s = 0, m2s = 1;
    if (m2d < m1d) { unsigned td = m1d; m1d = m2d; m2d = td; m1s = 1; m2s = 0; }
#pragma unroll
    for (int q = 2; q < 16; ++q) {
      unsigned dq = d[q];
      bool lt1 = dq < m1d, lt2 = dq < m2d;
      m2d = lt1 ? m1d : (lt2 ? dq : m2d);
      m2s = lt1 ? m1s : (lt2 ? q : m2s);
      m1d = lt1 ? dq : m1d;
      m1s = lt1 ? q : m1s;
    }
    unsigned lmd = m1d;
    int lms = m1s;
    unsigned rmask = 0;
    bool stale = false;
    float msum = 0.f;
#pragma unroll 1
    for (int kk = 0; kk < 9; ++kk) {
      unsigned g = bmin32(lmd);
      bool eq = (lmd == g);
      unsigned long long mask = __ballot(eq);
      unsigned cc = ((unsigned)lane << 2) | ((unsigned)(lms >> 2) << 8) |
                    (unsigned)(lms & 3);     // cand index c = 4*lane+256e+j
      unsigned wc;
      if (__popcll(mask) == 1) {             // unique min dist (common)
        wc = (unsigned)__shfl((int)cc, (int)(__ffsll((long long)mask) - 1), 64);
      } else {                               // exact fp tie: min index
        unsigned tc = eq ? cc : 0xFFFFFFFFu;
        wc = bmin32(tc);
      }
      msum += __uint_as_float(
          (unsigned)cbuf[lane * CBUF_STRIDE + (int)wc] << 16);
      if (eq && cc == wc) {                  // this lane consumed its min
        rmask |= 1u << lms;
        if (!stale) { lmd = m2d; lms = m2s; stale = true; }
        else {                               // rare: rescan alive slots
          unsigned bd = 0xFFFFFFFFu; int bs = 0;
#pragma unroll
          for (int q = 0; q < 16; ++q) {
            bool alive = ((rmask >> q) & 1u) == 0u;
            bool take = alive && (d[q] < bd);
            bd = take ? d[q] : bd;
            bs = take ? q : bs;
          }
          lmd = bd; lms = bs;
        }
      }
    }
    ms[r] = msum / 9.0f;
  }

  // -------- phase 3: out = mean@Wl^T + bl + self@Wr^T (two W passes) -------
  float accL[2] = {0.f, 0.f};
  {
    float4 wq[16];
#pragma unroll
    for (int k = 0; k < 16; ++k)
      wq[k] = *(const float4*)&Wl[(lane << 6) + (k << 2)];
#pragma unroll
    for (int c = 0; c < 64; ++c) {
      const float* wp = (const float*)&wq[c >> 2];
      float wv = wp[c & 3];
      accL[0] = fmaf(rdlane(ms[0], c), wv, accL[0]);
      accL[1] = fmaf(rdlane(ms[1], c), wv, accL[1]);
    }
  }
  float accR[2] = {0.f, 0.f};
  {
    float4 wq[16];
#pragma unroll
    for (int k = 0; k < 16; ++k)
      wq[k] = *(const float4*)&Wr[(lane << 6) + (k << 2)];
#pragma unroll
    for (int c = 0; c < 64; ++c) {
      const float* wp = (const float*)&wq[c >> 2];
      float wv = wp[c & 3];
      accR[0] = fmaf(rdlane(rowf[0], c), wv, accR[0]);
      accR[1] = fmaf(rdlane(rowf[1], c), wv, accR[1]);
    }
  }
  float bias = bl[lane];
#pragma unroll
  for (int r = 0; r < 2; ++r) {
    int n = n0 + (w << 1) + r;
    out[((size_t)n << 6) + lane] = accL[r] + accR[r] + bias;
  }
}

// ---------------------------------------------------------------------------
extern "C" void kernel_launch(void* const* d_in, const int* in_sizes, int n_in,
                              void* d_out, int out_size, void* d_ws, size_t ws_size,
                              hipStream_t stream) {
  const float* x  = (const float*)d_in[0];   // (8,64,32,32)
  const float* Wl = (const float*)d_in[1];   // (64,64)
  const float* bl = (const float*)d_in[2];   // (64,)
  const float* Wr = (const float*)d_in[3];   // (64,64)
  float* out = (float*)d_out;                // (8192,64)

  // dynamic LDS > 64 KB: opt in every call (idempotent, capture-safe)
  hipFuncSetAttribute((const void*)k_fused,
                      hipFuncAttributeMaxDynamicSharedMemorySize, CBUF_BYTES);
  k_fused<<<256, 1024, CBUF_BYTES, stream>>>(x, Wl, bl, Wr, out);
}